// Round 5
// baseline (247.270 us; speedup 1.0000x reference)
//
#include <hip/hip_runtime.h>
#include <cstdint>
#include <cstddef>

typedef __attribute__((ext_vector_type(8))) __bf16 bf16x8;
typedef __attribute__((ext_vector_type(4))) float f32x4;

#define MFMA16(a, b, c) __builtin_amdgcn_mfma_f32_16x16x32_bf16((a), (b), (c), 0, 0, 0)

__device__ __forceinline__ float fast_tanh(float z) {
    float e = __expf(2.0f * z);
    return 1.0f - 2.0f * __builtin_amdgcn_rcpf(e + 1.0f);
}
__device__ __forceinline__ float fast_sigmoid(float z) {
    return __builtin_amdgcn_rcpf(1.0f + __expf(-z));
}

__device__ __forceinline__ unsigned pk2(float a, float b) {
    union { __bf16 h[2]; unsigned u; } p;
    p.h[0] = (__bf16)a;
    p.h[1] = (__bf16)b;
    return p.u;
}

__device__ __forceinline__ bf16x8 cvt8(float4 a, float4 b) {
    bf16x8 f;
    f[0] = (__bf16)a.x; f[1] = (__bf16)a.y; f[2] = (__bf16)a.z; f[3] = (__bf16)a.w;
    f[4] = (__bf16)b.x; f[5] = (__bf16)b.y; f[6] = (__bf16)b.z; f[7] = (__bf16)b.w;
    return f;
}

// weight A-fragment: lane holds row `row`, k = k0..k0+7 (row-major W[64][64])
__device__ __forceinline__ bf16x8 ldwfrag(const float* __restrict__ W, int row, int k0) {
    const float4 a = *(const float4*)(W + row * 64 + k0);
    const float4 b = *(const float4*)(W + row * 64 + k0 + 4);
    bf16x8 f;
    f[0] = (__bf16)a.x; f[1] = (__bf16)a.y; f[2] = (__bf16)a.z; f[3] = (__bf16)a.w;
    f[4] = (__bf16)b.x; f[5] = (__bf16)b.y; f[6] = (__bf16)b.z; f[7] = (__bf16)b.w;
    return f;
}

// Cox-de Boor, order 3, 12 knots -> 8 basis funcs (exact reference replication).
__device__ __forceinline__ void bspl8(float x, const float* kn, float* B) {
    float b[11];
#pragma unroll
    for (int m = 0; m < 11; ++m)
        b[m] = (x >= kn[m] && x < kn[m + 1]) ? 1.0f : 0.0f;
#pragma unroll
    for (int d = 1; d <= 3; ++d) {
#pragma unroll
        for (int m = 0; m + d < 11; ++m) {
            float lf = (x - kn[m]) / (kn[m + d] - kn[m]) * b[m];
            float rt = (kn[m + d + 1] - x) / (kn[m + d + 1] - kn[m + 1]) * b[m + 1];
            b[m] = lf + rt;
        }
    }
#pragma unroll
    for (int m = 0; m < 8; ++m) B[m] = b[m];
}

// One block = 4 samples, 256 steps of both RNN layers + KAN. 512 blocks fill
// all 256 CUs at 2 blocks/CU (2 waves/SIMD) so independent barrier groups
// hide each other's latency. MFMA B-columns replicated 4x (col c = sample
// c&3): per-wave instruction stream identical to the 16-sample version.
// Replica lanes (sc>=4) write h to unused LDS rows; reads broadcast.
__global__ __launch_bounds__(256, 1) void rnn_kan_v5(
    const float* __restrict__ x,
    const float* __restrict__ wih0, const float* __restrict__ whh0,
    const float* __restrict__ bih0, const float* __restrict__ bhh0,
    const float* __restrict__ wih1, const float* __restrict__ whh1,
    const float* __restrict__ bih1, const float* __restrict__ bhh1,
    const float* __restrict__ grid0, const float* __restrict__ coef0,
    const float* __restrict__ sb0, const float* __restrict__ sp0,
    const float* __restrict__ grid1, const float* __restrict__ coef1,
    const float* __restrict__ sb1, const float* __restrict__ sp1,
    float* __restrict__ out)
{
    __shared__ __align__(16) unsigned char s_h1[2][2048]; // h1 bf16, dbuf (rows sc>=4 unused)
    __shared__ __align__(16) unsigned char s_h2[2][2048]; // h2 bf16
    __shared__ __align__(16) float s_hf[16][68];          // final h2 fp32 (rows 0-3 used)
    __shared__ __align__(16) float s_bas[256][12];        // KAN0 basis[8] + silu at [8]
    __shared__ __align__(16) float s_e[4][17];            // KAN1 edge values

    const int tid  = threadIdx.x;
    const int wv   = tid >> 6;
    const int lane = tid & 63;
    const int sc   = lane & 15;   // MFMA col
    const int gr   = lane >> 4;   // 16-lane group
    const int samp = sc & 3;      // sample this col carries
    const int s0   = blockIdx.x << 2;

    // weights -> A-fragments (row = 16wv+sc, k = 32kt+8gr..+7)
    const int wrow = 16 * wv + sc;
    const int kofs = 8 * gr;
    bf16x8 fWih0[2], fWhh0[2], fWih1[2], fWhh1[2];
#pragma unroll
    for (int kt = 0; kt < 2; ++kt) {
        fWih0[kt] = ldwfrag(wih0, wrow, 32 * kt + kofs);
        fWhh0[kt] = ldwfrag(whh0, wrow, 32 * kt + kofs);
        fWih1[kt] = ldwfrag(wih1, wrow, 32 * kt + kofs);
        fWhh1[kt] = ldwfrag(whh1, wrow, 32 * kt + kofs);
    }
    f32x4 b0v, b1v;
#pragma unroll
    for (int i = 0; i < 4; ++i) {
        const int h = 16 * wv + 4 * gr + i;
        b0v[i] = bih0[h] + bhh0[h];
        b1v[i] = bih1[h] + bhh1[h];
    }

    // LDS h-buffer byte offsets (XOR-swizzle on byte bits 4..6)
    const unsigned offW  = sc * 128 + (((unsigned)(32 * wv + 8 * gr)) ^ ((unsigned)(sc & 7) << 4));
    const unsigned offR0 = samp * 128 + (((unsigned)(16 * gr)) ^ ((unsigned)samp << 4));
    const unsigned offR1 = samp * 128 + (((unsigned)(64 + 16 * gr)) ^ ((unsigned)samp << 4));

    // x gather base: lane reads sample samp, k = 8gr..+7 (+32 for kt1)
    const float* xb = x + (size_t)(s0 + samp) * 16384 + kofs;

    // ---- prologue: x[0] -> xz; ra = x[1], rb = x[2] raw
    float4 q0 = *(const float4*)(xb);      float4 q1 = *(const float4*)(xb + 4);
    float4 q2 = *(const float4*)(xb + 32); float4 q3 = *(const float4*)(xb + 36);
    float4 ra0 = *(const float4*)(xb + 64),  ra1 = *(const float4*)(xb + 68);
    float4 ra2 = *(const float4*)(xb + 96),  ra3 = *(const float4*)(xb + 100);
    float4 rb0 = *(const float4*)(xb + 128), rb1 = *(const float4*)(xb + 132);
    float4 rb2 = *(const float4*)(xb + 160), rb3 = *(const float4*)(xb + 164);

    f32x4 xz = MFMA16(fWih0[0], cvt8(q0, q1), b0v);
    xz = MFMA16(fWih0[1], cvt8(q2, q3), xz);

    // ---- peel t=0: h1[0] = tanh(xz)  (h1[-1]=0)
    {
        float v[4];
#pragma unroll
        for (int i = 0; i < 4; ++i) v[i] = fast_tanh(xz[i]);
        uint2 pw; pw.x = pk2(v[0], v[1]); pw.y = pk2(v[2], v[3]);
        *(uint2*)((char*)(&s_h1[0][0]) + offW) = pw;
    }
    // xz for t=1 from ra; shift ring; load x[3]
    xz = MFMA16(fWih0[0], cvt8(ra0, ra1), b0v);
    xz = MFMA16(fWih0[1], cvt8(ra2, ra3), xz);
    ra0 = rb0; ra1 = rb1; ra2 = rb2; ra3 = rb3;
    rb0 = *(const float4*)(xb + 192); rb1 = *(const float4*)(xb + 196);
    rb2 = *(const float4*)(xb + 224); rb3 = *(const float4*)(xb + 228);

    asm volatile("s_waitcnt lgkmcnt(0)" ::: "memory");
    __builtin_amdgcn_s_barrier();
    asm volatile("" ::: "memory");

    bf16x8 h1f0 = *(const bf16x8*)((const char*)(&s_h1[0][0]) + offR0);
    bf16x8 h1f1 = *(const bf16x8*)((const char*)(&s_h1[0][0]) + offR1);
    f32x4 h2z = b1v;   // = b1 + Whh1 @ h2[-1] (zero)

    // ---- main loop t = 1..255
#pragma unroll 2
    for (int t = 1; t < 256; ++t) {
        const int par = t & 1;
        // h1[t] preact = xz + Whh0 @ h1[t-1]
        f32x4 z1 = MFMA16(fWhh0[0], h1f0, xz);
        z1 = MFMA16(fWhh0[1], h1f1, z1);
        // h2[t-1] preact = h2z + Wih1 @ h1[t-1]
        f32x4 z2 = MFMA16(fWih1[0], h1f0, h2z);
        z2 = MFMA16(fWih1[1], h1f1, z2);

        float v1[4], v2[4];
#pragma unroll
        for (int i = 0; i < 4; ++i) v1[i] = fast_tanh(z1[i]);
        uint2 pw1; pw1.x = pk2(v1[0], v1[1]); pw1.y = pk2(v1[2], v1[3]);
        *(uint2*)((char*)(&s_h1[par][0]) + offW) = pw1;
#pragma unroll
        for (int i = 0; i < 4; ++i) v2[i] = fast_tanh(z2[i]);
        uint2 pw2; pw2.x = pk2(v2[0], v2[1]); pw2.y = pk2(v2[2], v2[3]);
        *(uint2*)((char*)(&s_h2[par][0]) + offW) = pw2;

        // shadow: xz for t+1; ring shift; prefetch x[t+3]
        xz = MFMA16(fWih0[0], cvt8(ra0, ra1), b0v);
        xz = MFMA16(fWih0[1], cvt8(ra2, ra3), xz);
        ra0 = rb0; ra1 = rb1; ra2 = rb2; ra3 = rb3;
        {
            const float* pn = xb + (size_t)((t + 3 > 255) ? 255 : t + 3) * 64;
            rb0 = *(const float4*)(pn);      rb1 = *(const float4*)(pn + 4);
            rb2 = *(const float4*)(pn + 32); rb3 = *(const float4*)(pn + 36);
        }

        asm volatile("s_waitcnt lgkmcnt(0)" ::: "memory");
        __builtin_amdgcn_s_barrier();
        asm volatile("" ::: "memory");

        // reads: h2 first (feeds h2z immediately), then h1
        bf16x8 h2f0 = *(const bf16x8*)((const char*)(&s_h2[par][0]) + offR0);
        bf16x8 h2f1 = *(const bf16x8*)((const char*)(&s_h2[par][0]) + offR1);
        h1f0 = *(const bf16x8*)((const char*)(&s_h1[par][0]) + offR0);
        h1f1 = *(const bf16x8*)((const char*)(&s_h1[par][0]) + offR1);

        // shadow for next iter: h2z = b1 + Whh1 @ h2[t-1]
        h2z = MFMA16(fWhh1[0], h2f0, b1v);
        h2z = MFMA16(fWhh1[1], h2f1, h2z);
    }

    // ---- final h2[255] = tanh(h2z + Wih1 @ h1[255]) -> fp32 LDS
    {
        f32x4 z2 = MFMA16(fWih1[0], h1f0, h2z);
        z2 = MFMA16(fWih1[1], h1f1, z2);
        f32x4 hv;
#pragma unroll
        for (int i = 0; i < 4; ++i) hv[i] = fast_tanh(z2[i]);
        *(f32x4*)(&s_hf[sc][16 * wv + 4 * gr]) = hv;   // rows 0-3 carry samples 0-3
    }
    __syncthreads();

    // ---- KAN epilogue (4 samples)
    float kn0[12], kn1[12];
#pragma unroll
    for (int m = 0; m < 12; ++m) { kn0[m] = grid0[m]; kn1[m] = grid1[m]; }

    // K1: basis + silu for all 256 (i, s) pairs, one per thread
    {
        const int q = tid;
        const int i = q >> 2, s = q & 3;
        const float v = s_hf[s][i];
        float B[8];
        bspl8(v, kn0, B);
        *(float4*)(&s_bas[q][0]) = make_float4(B[0], B[1], B[2], B[3]);
        *(float4*)(&s_bas[q][4]) = make_float4(B[4], B[5], B[6], B[7]);
        s_bas[q][8] = v * fast_sigmoid(v);
    }
    __syncthreads();

    // K2: KAN0 out[s][o]; K3: KAN1 edge for (s,o) — 64 threads
    if (tid < 64) {
        const int s = tid >> 4, o = tid & 15;
        float acc = 0.0f;
        for (int i = 0; i < 64; ++i) {
            const int q = (i << 2) + s;
            const float4 B0 = *(const float4*)(&s_bas[q][0]);
            const float4 B1 = *(const float4*)(&s_bas[q][4]);
            const float sil = s_bas[q][8];
            const float* cp = coef0 + i * 128 + o * 8;
            const float4 c0 = *(const float4*)cp;
            const float4 c1 = *(const float4*)(cp + 4);
            const float spl = B0.x * c0.x + B0.y * c0.y + B0.z * c0.z + B0.w * c0.w +
                              B1.x * c1.x + B1.y * c1.y + B1.z * c1.z + B1.w * c1.w;
            acc += sil * sb0[(i << 4) + o] + sp0[(i << 4) + o] * spl;
        }
        float B[8];
        bspl8(acc, kn1, B);
        const float* cp = coef1 + o * 8;
        float spl = 0.0f;
#pragma unroll
        for (int k = 0; k < 8; ++k) spl += B[k] * cp[k];
        s_e[s][o] = (acc * fast_sigmoid(acc)) * sb1[o] + sp1[o] * spl;
    }
    __syncthreads();

    // K4: reduce 16 edges per sample, sigmoid, store
    if (tid < 4) {
        float sum = 0.0f;
#pragma unroll
        for (int o = 0; o < 16; ++o) sum += s_e[tid][o];
        out[s0 + tid] = fast_sigmoid(sum);
    }
}

extern "C" void kernel_launch(void* const* d_in, const int* in_sizes, int n_in,
                              void* d_out, int out_size, void* d_ws, size_t ws_size,
                              hipStream_t stream) {
    (void)n_in; (void)out_size; (void)d_ws; (void)ws_size;
    const int B = in_sizes[0] / (256 * 64);   // 2048
    const int grid = B / 4;                   // 512 blocks of 4 samples
    rnn_kan_v5<<<dim3(grid), dim3(256), 0, stream>>>(
        (const float*)d_in[0],
        (const float*)d_in[1], (const float*)d_in[2], (const float*)d_in[3], (const float*)d_in[4],
        (const float*)d_in[5], (const float*)d_in[6], (const float*)d_in[7], (const float*)d_in[8],
        (const float*)d_in[9], (const float*)d_in[10], (const float*)d_in[11], (const float*)d_in[12],
        (const float*)d_in[13], (const float*)d_in[14], (const float*)d_in[15], (const float*)d_in[16],
        (float*)d_out);
}

// Round 7
// 146.478 us; speedup vs baseline: 1.6881x; 1.6881x over previous
//
#include <hip/hip_runtime.h>
#include <cstdint>
#include <cstddef>

typedef __attribute__((ext_vector_type(8))) __bf16 bf16x8;
typedef __attribute__((ext_vector_type(4))) float f32x4;

#define MFMA16(a, b, c) __builtin_amdgcn_mfma_f32_16x16x32_bf16((a), (b), (c), 0, 0, 0)

__device__ __forceinline__ float fast_tanh(float z) {
    float e = __expf(2.0f * z);
    return 1.0f - 2.0f * __builtin_amdgcn_rcpf(e + 1.0f);
}
__device__ __forceinline__ float fast_sigmoid(float z) {
    return __builtin_amdgcn_rcpf(1.0f + __expf(-z));
}

// Guaranteed global (AS1) vector load -> global_load_dwordx4, vmcnt-only.
// (A generic-pointer load may compile to flat_load, which increments BOTH
// vmcnt and lgkmcnt -> our per-step lgkmcnt(0) would drain HBM prefetches.)
// Use ext_vector f32x4 (not HIP float4 class) so the AS(1) deref compiles.
__device__ __forceinline__ f32x4 gload4(const float* p) {
    return *(const __attribute__((address_space(1))) f32x4*)p;
}

__device__ __forceinline__ unsigned pk2(float a, float b) {
    union { __bf16 h[2]; unsigned u; } p;
    p.h[0] = (__bf16)a;
    p.h[1] = (__bf16)b;
    return p.u;
}

__device__ __forceinline__ bf16x8 cvt8(f32x4 a, f32x4 b) {
    bf16x8 f;
    f[0] = (__bf16)a[0]; f[1] = (__bf16)a[1]; f[2] = (__bf16)a[2]; f[3] = (__bf16)a[3];
    f[4] = (__bf16)b[0]; f[5] = (__bf16)b[1]; f[6] = (__bf16)b[2]; f[7] = (__bf16)b[3];
    return f;
}

// weight A-fragment: lane holds row `row`, k = k0..k0+7 (row-major W[64][64])
__device__ __forceinline__ bf16x8 ldwfrag(const float* __restrict__ W, int row, int k0) {
    const f32x4 a = *(const f32x4*)(W + row * 64 + k0);
    const f32x4 b = *(const f32x4*)(W + row * 64 + k0 + 4);
    return cvt8(a, b);
}

// Cox-de Boor, order 3, 12 knots -> 8 basis funcs (exact reference replication).
__device__ __forceinline__ void bspl8(float x, const float* kn, float* B) {
    float b[11];
#pragma unroll
    for (int m = 0; m < 11; ++m)
        b[m] = (x >= kn[m] && x < kn[m + 1]) ? 1.0f : 0.0f;
#pragma unroll
    for (int d = 1; d <= 3; ++d) {
#pragma unroll
        for (int m = 0; m + d < 11; ++m) {
            float lf = (x - kn[m]) / (kn[m + d] - kn[m]) * b[m];
            float rt = (kn[m + d + 1] - x) / (kn[m + d + 1] - kn[m + 1]) * b[m + 1];
            b[m] = lf + rt;
        }
    }
#pragma unroll
    for (int m = 0; m < 8; ++m) B[m] = b[m];
}

// One block = 16 samples through 256 steps of both RNN layers + KAN.
// 4 waves; wave wv owns hidden rows [16wv,16wv+16). Layer-skewed (iter t makes
// h1[t], h2[t-1]) -> ONE barrier/step. x loaded AS(1) global->VGPR via a
// 3-slot register ring (loads 3 steps ahead, vmcnt-counted by the compiler;
// per-step lgkmcnt(0) covers ONLY the two ds_writes).
__global__ __launch_bounds__(256, 1) void rnn_kan_v6(
    const float* __restrict__ x,
    const float* __restrict__ wih0, const float* __restrict__ whh0,
    const float* __restrict__ bih0, const float* __restrict__ bhh0,
    const float* __restrict__ wih1, const float* __restrict__ whh1,
    const float* __restrict__ bih1, const float* __restrict__ bhh1,
    const float* __restrict__ grid0, const float* __restrict__ coef0,
    const float* __restrict__ sb0, const float* __restrict__ sp0,
    const float* __restrict__ grid1, const float* __restrict__ coef1,
    const float* __restrict__ sb1, const float* __restrict__ sp1,
    float* __restrict__ out)
{
    __shared__ __align__(16) unsigned char s_h[2][4096];  // par -> h1 (0..2047) | h2 (2048..4095)
    __shared__ __align__(16) float s_hf[16][68];          // final h2 fp32
    __shared__ __align__(16) float s_bas[1024][12];       // KAN0 basis[8] + silu at [8]
    __shared__ __align__(16) float s_e[16][17];           // KAN1 edge values

    const int tid  = threadIdx.x;
    const int wv   = tid >> 6;
    const int lane = tid & 63;
    const int sc   = lane & 15;   // MFMA col (= sample)
    const int gr   = lane >> 4;   // 16-lane group
    const int s0   = blockIdx.x << 4;

    // weights -> A-fragments (row = 16wv+sc, k = 32kt+8gr..+7)
    const int wrow = 16 * wv + sc;
    const int kofs = 8 * gr;
    bf16x8 fWih0[2], fWhh0[2], fWih1[2], fWhh1[2];
#pragma unroll
    for (int kt = 0; kt < 2; ++kt) {
        fWih0[kt] = ldwfrag(wih0, wrow, 32 * kt + kofs);
        fWhh0[kt] = ldwfrag(whh0, wrow, 32 * kt + kofs);
        fWih1[kt] = ldwfrag(wih1, wrow, 32 * kt + kofs);
        fWhh1[kt] = ldwfrag(whh1, wrow, 32 * kt + kofs);
    }
    f32x4 b0v, b1v, zv;
#pragma unroll
    for (int i = 0; i < 4; ++i) {
        const int h = 16 * wv + 4 * gr + i;
        b0v[i] = bih0[h] + bhh0[h];
        b1v[i] = bih1[h] + bhh1[h];
        zv[i] = 0.0f;
    }

    // LDS h-buffer byte offsets (XOR-swizzle on byte bits 4..6)
    const unsigned swz  = (unsigned)(sc & 7) << 4;
    const unsigned offW  = sc * 128 + (((unsigned)(32 * wv + 8 * gr)) ^ swz); // C write (b64)
    const unsigned offR0 = sc * 128 + (((unsigned)(16 * gr)) ^ swz);          // B-frag kt=0 (b128)
    const unsigned offR1 = sc * 128 + (((unsigned)(64 + 16 * gr)) ^ swz);     // B-frag kt=1

    // x gather base: lane reads sample sc, k = 8gr..+7 (+32 for kt1); 64B/step/sample
    const float* xb = x + (size_t)(s0 + sc) * 16384 + kofs;

    // ---- prologue
    f32x4 q0 = gload4(xb),        q1 = gload4(xb + 4);
    f32x4 q2 = gload4(xb + 32),   q3 = gload4(xb + 36);     // x[0]
    f32x4 p0 = gload4(xb + 64),   p1 = gload4(xb + 68);
    f32x4 p2 = gload4(xb + 96),   p3 = gload4(xb + 100);    // x[1]
    // ring slots: 0 -> x[2], 1 -> x[3], 2 -> x[4]
    f32x4 r0[3], r1[3], r2[3], r3[3];
#pragma unroll
    for (int j = 0; j < 3; ++j) {
        const float* pj = xb + (size_t)(2 + j) * 64;
        r0[j] = gload4(pj);      r1[j] = gload4(pj + 4);
        r2[j] = gload4(pj + 32); r3[j] = gload4(pj + 36);
    }

    f32x4 xz = MFMA16(fWih0[0], cvt8(q0, q1), b0v);
    xz = MFMA16(fWih0[1], cvt8(q2, q3), xz);

    // ---- peel t=0: h1[0] = tanh(xz)  (h1[-1]=0); h2 region [par0] zeroed = h2[-1]
    {
        float v[4];
#pragma unroll
        for (int i = 0; i < 4; ++i) v[i] = fast_tanh(xz[i]);
        uint2 pw; pw.x = pk2(v[0], v[1]); pw.y = pk2(v[2], v[3]);
        *(uint2*)((char*)(&s_h[0][0]) + offW) = pw;
    }
    // zero the h2 region of parity-0 buffer (h2[-1] = 0)
    *(uint2*)((char*)(&s_h[0][0]) + 2048 + offW) = make_uint2(0u, 0u);

    // xz for t=1 from x[1]
    xz = MFMA16(fWih0[0], cvt8(p0, p1), b0v);
    xz = MFMA16(fWih0[1], cvt8(p2, p3), xz);

    asm volatile("s_waitcnt lgkmcnt(0)" ::: "memory");
    __builtin_amdgcn_s_barrier();
    asm volatile("" ::: "memory");

    bf16x8 h1f0 = *(const bf16x8*)((const char*)(&s_h[0][0]) + offR0);
    bf16x8 h1f1 = *(const bf16x8*)((const char*)(&s_h[0][0]) + offR1);
    f32x4 h2z = b1v;   // = b1 + Whh1 @ h2[-1] (zero)

    // ---- main loop t = 1..255 (unroll 3 -> ring slot static)
#pragma unroll 3
    for (int t = 1; t < 256; ++t) {
        const int slot = (t - 1) % 3;           // holds x[t+1]
        char* hb = (char*)(&s_h[0][0]) + ((t & 1) << 12);

        // h1[t] preact: two parallel MFMA chains + add (critical cycle)
        f32x4 z1a = MFMA16(fWhh0[0], h1f0, xz);
        f32x4 z1b = MFMA16(fWhh0[1], h1f1, zv);
        // h2[t-1] preact (1 step of slack)
        f32x4 z2a = MFMA16(fWih1[0], h1f0, h2z);
        f32x4 z2b = MFMA16(fWih1[1], h1f1, zv);

        f32x4 z1 = z1a + z1b;
        float v1[4];
#pragma unroll
        for (int i = 0; i < 4; ++i) v1[i] = fast_tanh(z1[i]);
        uint2 pw1; pw1.x = pk2(v1[0], v1[1]); pw1.y = pk2(v1[2], v1[3]);
        *(uint2*)(hb + offW) = pw1;

        f32x4 z2 = z2a + z2b;
        float v2[4];
#pragma unroll
        for (int i = 0; i < 4; ++i) v2[i] = fast_tanh(z2[i]);
        uint2 pw2; pw2.x = pk2(v2[0], v2[1]); pw2.y = pk2(v2[2], v2[3]);
        *(uint2*)(hb + 2048 + offW) = pw2;

        // shadow: xz for t+1 from ring slot; refill slot with x[t+4]
        xz = MFMA16(fWih0[0], cvt8(r0[slot], r1[slot]), b0v);
        xz = MFMA16(fWih0[1], cvt8(r2[slot], r3[slot]), xz);
        {
            const float* pn = xb + (size_t)((t + 4 > 255) ? 255 : t + 4) * 64;
            r0[slot] = gload4(pn);      r1[slot] = gload4(pn + 4);
            r2[slot] = gload4(pn + 32); r3[slot] = gload4(pn + 36);
        }

        // wait covers ONLY the two ds_writes (x loads are vmcnt)
        asm volatile("s_waitcnt lgkmcnt(0)" ::: "memory");
        __builtin_amdgcn_s_barrier();
        asm volatile("" ::: "memory");

        // h1 first (feeds next z1 = critical cycle), then h2
        h1f0 = *(const bf16x8*)(hb + offR0);
        h1f1 = *(const bf16x8*)(hb + offR1);
        bf16x8 h2f0 = *(const bf16x8*)(hb + 2048 + offR0);
        bf16x8 h2f1 = *(const bf16x8*)(hb + 2048 + offR1);

        // shadow for next iter: h2z = b1 + Whh1 @ h2[t-1]
        h2z = MFMA16(fWhh1[0], h2f0, b1v);
        h2z = MFMA16(fWhh1[1], h2f1, h2z);
    }

    // ---- final h2[255] = tanh(h2z + Wih1 @ h1[255]) -> fp32 LDS
    {
        f32x4 z2a = MFMA16(fWih1[0], h1f0, h2z);
        f32x4 z2b = MFMA16(fWih1[1], h1f1, zv);
        f32x4 z2 = z2a + z2b;
        f32x4 hv;
#pragma unroll
        for (int i = 0; i < 4; ++i) hv[i] = fast_tanh(z2[i]);
        *(f32x4*)(&s_hf[sc][16 * wv + 4 * gr]) = hv;
    }
    __syncthreads();

    // ---- KAN epilogue
    float kn0[12], kn1[12];
#pragma unroll
    for (int m = 0; m < 12; ++m) { kn0[m] = grid0[m]; kn1[m] = grid1[m]; }

    // K1: basis + silu for all 1024 (i, s) pairs
    for (int q = tid; q < 1024; q += 256) {
        const int i = q >> 4, s = q & 15;
        const float v = s_hf[s][i];
        float B[8];
        bspl8(v, kn0, B);
        *(float4*)(&s_bas[q][0]) = make_float4(B[0], B[1], B[2], B[3]);
        *(float4*)(&s_bas[q][4]) = make_float4(B[4], B[5], B[6], B[7]);
        s_bas[q][8] = v * fast_sigmoid(v);
    }
    __syncthreads();

    // K2: KAN0 out[s][o]; K3: KAN1 edge for (s,o)
    {
        const int s = tid >> 4, o = tid & 15;
        float acc = 0.0f;
        for (int i = 0; i < 64; ++i) {
            const int q = (i << 4) + s;
            const float4 B0 = *(const float4*)(&s_bas[q][0]);
            const float4 B1 = *(const float4*)(&s_bas[q][4]);
            const float sil = s_bas[q][8];
            const float* cp = coef0 + i * 128 + o * 8;
            const float4 c0 = *(const float4*)cp;
            const float4 c1 = *(const float4*)(cp + 4);
            const float spl = B0.x * c0.x + B0.y * c0.y + B0.z * c0.z + B0.w * c0.w +
                              B1.x * c1.x + B1.y * c1.y + B1.z * c1.z + B1.w * c1.w;
            acc += sil * sb0[(i << 4) + o] + sp0[(i << 4) + o] * spl;
        }
        float B[8];
        bspl8(acc, kn1, B);
        const float* cp = coef1 + o * 8;
        float spl = 0.0f;
#pragma unroll
        for (int k = 0; k < 8; ++k) spl += B[k] * cp[k];
        s_e[s][o] = (acc * fast_sigmoid(acc)) * sb1[o] + sp1[o] * spl;
    }
    __syncthreads();

    // K4: reduce 16 edges per sample, sigmoid, store
    if (tid < 16) {
        float sum = 0.0f;
#pragma unroll
        for (int o = 0; o < 16; ++o) sum += s_e[tid][o];
        out[s0 + tid] = fast_sigmoid(sum);
    }
}

extern "C" void kernel_launch(void* const* d_in, const int* in_sizes, int n_in,
                              void* d_out, int out_size, void* d_ws, size_t ws_size,
                              hipStream_t stream) {
    (void)n_in; (void)out_size; (void)d_ws; (void)ws_size;
    const int B = in_sizes[0] / (256 * 64);   // 2048
    const int grid = B / 16;                  // 128 blocks of 16 samples
    rnn_kan_v6<<<dim3(grid), dim3(256), 0, stream>>>(
        (const float*)d_in[0],
        (const float*)d_in[1], (const float*)d_in[2], (const float*)d_in[3], (const float*)d_in[4],
        (const float*)d_in[5], (const float*)d_in[6], (const float*)d_in[7], (const float*)d_in[8],
        (const float*)d_in[9], (const float*)d_in[10], (const float*)d_in[11], (const float*)d_in[12],
        (const float*)d_in[13], (const float*)d_in[14], (const float*)d_in[15], (const float*)d_in[16],
        (float*)d_out);
}